// Round 1
// baseline (48.883 us; speedup 1.0000x reference)
//
#include <hip/hip_runtime.h>
#include <math.h>

#define BB 16
#define NN 256
#define DD 32

// ---------------------------------------------------------------------------
// Kernel A: per-node precompute.
//   u[b,n,:] = x[b,n,:] @ W_out[0:32, :]        (sender half)
//   v[b,n,:] = x[b,n,:] @ W_out[32:64, :] + b_out   (receiver half, bias folded)
// 8 nodes per 256-thread block; thread = (node_in_block, d).
// ---------------------------------------------------------------------------
__global__ __launch_bounds__(256) void precompute_uv(
    const float* __restrict__ x,
    const float* __restrict__ W_out,
    const float* __restrict__ b_out,
    float* __restrict__ u,
    float* __restrict__ v)
{
    int t = threadIdx.x;
    int pos = blockIdx.x * 8 + (t >> 5);   // global node index b*NN + n
    int d = t & 31;
    const float* xp = x + (size_t)pos * DD;
    float su = 0.f, sv = 0.f;
#pragma unroll
    for (int k = 0; k < DD; ++k) {
        float xv = xp[k];
        su += xv * W_out[k * DD + d];
        sv += xv * W_out[(k + DD) * DD + d];
    }
    u[(size_t)pos * DD + d] = su;
    v[(size_t)pos * DD + d] = sv + b_out[d];
}

// ---------------------------------------------------------------------------
// Kernel B: one block per (b, i) row; thread j in [0,256) handles pair (i,j).
//   h   = relu(u_j + v_i)            (b_out already folded into v)
//   e   = relu(h . W_cat + b_cat)
//   m_lin = (i==j) ? 0 : e
//   m_prod = x_i . x_j
//   w = sigmoid(relu([m_lin,m_prod]@W_f1 + b_f1) @ W_f2 + b_f2)
//   m = w*m_lin + (1-w)*m_prod
// Writes m, and per-row sum / sumsq (deterministic block reduction).
// ---------------------------------------------------------------------------
__global__ __launch_bounds__(256) void pair_kernel(
    const float* __restrict__ x,
    const float* __restrict__ u,
    const float* __restrict__ v,
    const float* __restrict__ W_cat,
    const float* __restrict__ b_cat,
    const float* __restrict__ W_f1,
    const float* __restrict__ b_f1,
    const float* __restrict__ W_f2,
    const float* __restrict__ b_f2,
    float* __restrict__ m_out,
    float* __restrict__ rowsum_out,
    float* __restrict__ rowsq_out)
{
    __shared__ float vi[DD], xi[DD], wcat[DD];
    __shared__ float wf1a[8], wf1b[8], bf1[8], wf2[8];
    __shared__ float red[8];

    int j  = threadIdx.x;
    int bi = blockIdx.x;          // b*NN + i
    int b  = bi >> 8;
    int i  = bi & 255;

    if (j < DD) {
        vi[j]   = v[(size_t)bi * DD + j];
        xi[j]   = x[(size_t)bi * DD + j];
        wcat[j] = W_cat[j];
    } else if (j < DD + 8) {
        int k = j - DD;
        wf1a[k] = W_f1[k];        // W_f1[0, k]
        wf1b[k] = W_f1[8 + k];    // W_f1[1, k]
        bf1[k]  = b_f1[k];
        wf2[k]  = W_f2[k];
    }
    __syncthreads();

    const float4* up4 = (const float4*)(u + (size_t)(b * NN + j) * DD);
    const float4* xp4 = (const float4*)(x + (size_t)(b * NN + j) * DD);

    float e = 0.f, mprod = 0.f;
#pragma unroll
    for (int q = 0; q < 8; ++q) {
        float4 uu = up4[q];
        float4 xx = xp4[q];
        int d0 = q * 4;
        e += fmaxf(uu.x + vi[d0 + 0], 0.f) * wcat[d0 + 0];
        e += fmaxf(uu.y + vi[d0 + 1], 0.f) * wcat[d0 + 1];
        e += fmaxf(uu.z + vi[d0 + 2], 0.f) * wcat[d0 + 2];
        e += fmaxf(uu.w + vi[d0 + 3], 0.f) * wcat[d0 + 3];
        mprod += xx.x * xi[d0 + 0] + xx.y * xi[d0 + 1]
               + xx.z * xi[d0 + 2] + xx.w * xi[d0 + 3];
    }
    e = fmaxf(e + b_cat[0], 0.f);
    float mlin = (j == i) ? 0.f : e;

    float s = b_f2[0];
#pragma unroll
    for (int k = 0; k < 8; ++k) {
        float z = fmaxf(mlin * wf1a[k] + mprod * wf1b[k] + bf1[k], 0.f);
        s += z * wf2[k];
    }
    float w = 1.f / (1.f + expf(-s));
    float m = w * mlin + (1.f - w) * mprod;

    m_out[(size_t)bi * NN + j] = m;

    // deterministic block reduction: wave64 shuffle, then LDS across 4 waves
    float sm = m, sq = m * m;
#pragma unroll
    for (int off = 32; off; off >>= 1) {
        sm += __shfl_down(sm, off);
        sq += __shfl_down(sq, off);
    }
    int wave = j >> 6;
    if ((j & 63) == 0) { red[wave] = sm; red[4 + wave] = sq; }
    __syncthreads();
    if (j == 0) {
        float rowsum = red[0] + red[1] + red[2] + red[3];
        float rowsq  = red[4] + red[5] + red[6] + red[7];
        rowsum_out[bi] = rowsum;
        rowsq_out[bi]  = rowsq;
    }
}

// ---------------------------------------------------------------------------
// Kernel C: per-batch stats. One block per batch (256 threads = 256 rows).
// With m2[i,j] = m[i,j] + r_i  (r_i = rowmean):
//   sum(m2)  = 2 * sum(m)
//   sum(m2^2)= sum(m^2) + 3*N*sum_i(r_i^2)
// stats[2b] = mu, stats[2b+1] = rsqrt(var + 1e-5)
// ---------------------------------------------------------------------------
__global__ __launch_bounds__(256) void stats_kernel(
    const float* __restrict__ rowsum,
    const float* __restrict__ rowsq,
    float* __restrict__ stats)
{
    __shared__ float red[12];
    int b = blockIdx.x;
    int i = threadIdx.x;
    float rs = rowsum[b * NN + i];
    float rq = rowsq[b * NN + i];
    float r  = rs * (1.f / NN);
    float sM = rs, sQ = rq, sR = r * r;
#pragma unroll
    for (int off = 32; off; off >>= 1) {
        sM += __shfl_down(sM, off);
        sQ += __shfl_down(sQ, off);
        sR += __shfl_down(sR, off);
    }
    int wave = i >> 6;
    if ((i & 63) == 0) { red[wave] = sM; red[4 + wave] = sQ; red[8 + wave] = sR; }
    __syncthreads();
    if (i == 0) {
        float sumM  = red[0] + red[1] + red[2] + red[3];
        float sumQ  = red[4] + red[5] + red[6] + red[7];
        float sumR2 = red[8] + red[9] + red[10] + red[11];
        const float invNN2 = 1.f / ((float)NN * (float)NN);
        float mu  = 2.f * sumM * invNN2;
        float ex2 = (sumQ + 3.f * (float)NN * sumR2) * invNN2;
        float var = ex2 - mu * mu;
        stats[2 * b]     = mu;
        stats[2 * b + 1] = rsqrtf(var + 1e-5f);
    }
}

// ---------------------------------------------------------------------------
// Kernel D: finalize. out[b,i,j] = (m[b,i,j] + r_i - mu_b) * rstd_b
// One block per (b,i) row.
// ---------------------------------------------------------------------------
__global__ __launch_bounds__(256) void finalize_kernel(
    const float* __restrict__ m_in,
    const float* __restrict__ rowsum,
    const float* __restrict__ stats,
    float* __restrict__ out)
{
    int bi = blockIdx.x;
    int b  = bi >> 8;
    int j  = threadIdx.x;
    float mu   = stats[2 * b];
    float rstd = stats[2 * b + 1];
    float r    = rowsum[bi] * (1.f / NN);
    float m    = m_in[(size_t)bi * NN + j];
    out[(size_t)bi * NN + j] = (m + r - mu) * rstd;
}

extern "C" void kernel_launch(void* const* d_in, const int* in_sizes, int n_in,
                              void* d_out, int out_size, void* d_ws, size_t ws_size,
                              hipStream_t stream)
{
    const float* x     = (const float*)d_in[0];
    const float* W_out = (const float*)d_in[1];
    const float* b_out = (const float*)d_in[2];
    const float* W_cat = (const float*)d_in[3];
    const float* b_cat = (const float*)d_in[4];
    const float* W_f1  = (const float*)d_in[5];
    const float* b_f1  = (const float*)d_in[6];
    const float* W_f2  = (const float*)d_in[7];
    const float* b_f2  = (const float*)d_in[8];

    float* ws     = (float*)d_ws;
    float* u      = ws;                        // BB*NN*DD
    float* v      = u + BB * NN * DD;          // BB*NN*DD
    float* m      = v + BB * NN * DD;          // BB*NN*NN
    float* rowsum = m + (size_t)BB * NN * NN;  // BB*NN
    float* rowsq  = rowsum + BB * NN;          // BB*NN
    float* stats  = rowsq + BB * NN;           // 2*BB

    precompute_uv<<<BB * NN / 8, 256, 0, stream>>>(x, W_out, b_out, u, v);
    pair_kernel<<<BB * NN, 256, 0, stream>>>(x, u, v, W_cat, b_cat,
                                             W_f1, b_f1, W_f2, b_f2,
                                             m, rowsum, rowsq);
    stats_kernel<<<BB, 256, 0, stream>>>(rowsum, rowsq, stats);
    finalize_kernel<<<BB * NN, 256, 0, stream>>>(m, rowsum, stats, (float*)d_out);
}

// Round 2
// 24.401 us; speedup vs baseline: 2.0033x; 2.0033x over previous
//
#include <hip/hip_runtime.h>
#include <math.h>

#define BB 16
#define NN 256
#define DD 32
#define ROWS 8   // rows per pair2 block

// ---------------------------------------------------------------------------
// K1: per-node precompute.
//   u[b,n,:] = x[b,n,:] @ W_out[0:32, :]          (sender half)
//   v[b,n,:] = x[b,n,:] @ W_out[32:64, :] + b_out (receiver half, bias folded)
// 8 nodes per 256-thread block; thread = (node_in_block, d). Coalesced W reads,
// broadcast x reads, coalesced u/v writes.
// ---------------------------------------------------------------------------
__global__ __launch_bounds__(256) void precompute_uv(
    const float* __restrict__ x,
    const float* __restrict__ W_out,
    const float* __restrict__ b_out,
    float* __restrict__ u,
    float* __restrict__ v)
{
    int t = threadIdx.x;
    int pos = blockIdx.x * 8 + (t >> 5);   // global node index b*NN + n
    int d = t & 31;
    const float* xp = x + (size_t)pos * DD;
    float su = 0.f, sv = 0.f;
#pragma unroll
    for (int k = 0; k < DD; ++k) {
        float xv = xp[k];
        su += xv * W_out[k * DD + d];
        sv += xv * W_out[(k + DD) * DD + d];
    }
    u[(size_t)pos * DD + d] = su;
    v[(size_t)pos * DD + d] = sv + b_out[d];
}

// ---------------------------------------------------------------------------
// K2: pair kernel. Block = (b, rowgroup of 8 rows), 512 threads.
// Phase 0: stage x[b] (32KB) and u[b] (32KB) into LDS with coalesced global
//          loads; XOR-swizzle the 16B granule within each 128B row
//          (phys_chunk = chunk ^ (row&7)) so phase-1's lane-per-row
//          ds_read_b128 is spread across banks (T2).
// Phase 1: thread (tr=t>>8, j=t&255) handles 4 rows x 1 col:
//   h = relu(u_j + v_i); e = relu(h.W_cat + b_cat); mlin = (i==j)?0:e
//   mprod = x_i . x_j
//   w = sigmoid(relu([mlin,mprod]@W_f1+b_f1)@W_f2+b_f2)
//   m = w*mlin + (1-w)*mprod
// Writes m + per-row sum/sumsq (deterministic wave-shuffle tree).
// ---------------------------------------------------------------------------
__global__ __launch_bounds__(512) void pair2_kernel(
    const float* __restrict__ x,
    const float* __restrict__ u,
    const float* __restrict__ v,
    const float* __restrict__ W_cat,
    const float* __restrict__ b_cat,
    const float* __restrict__ W_f1,
    const float* __restrict__ b_f1,
    const float* __restrict__ W_f2,
    const float* __restrict__ b_f2,
    float* __restrict__ m_out,
    float* __restrict__ rowsum_out,
    float* __restrict__ rowsq_out)
{
    __shared__ float4 lu4[NN * 8];      // 32KB, swizzled
    __shared__ float4 lx4[NN * 8];      // 32KB, swizzled
    __shared__ float4 lv4[ROWS * 8];    // 1KB, linear
    __shared__ float red0[ROWS][4];
    __shared__ float red1[ROWS][4];

    int t  = threadIdx.x;
    int b  = blockIdx.x >> 5;           // 32 rowgroups per batch
    int i0 = (blockIdx.x & 31) * ROWS;

    const float4* xb4 = (const float4*)(x + (size_t)b * NN * DD);
    const float4* ub4 = (const float4*)(u + (size_t)b * NN * DD);
#pragma unroll
    for (int k = 0; k < 4; ++k) {       // 2048 float4s / 512 threads
        int f = k * 512 + t;
        int n = f >> 3, c = f & 7;
        int p = n * 8 + (c ^ (n & 7));  // swizzled store
        lx4[p] = xb4[f];
        lu4[p] = ub4[f];
    }
    if (t < ROWS * 8)
        lv4[t] = ((const float4*)(v + ((size_t)b * NN + i0) * DD))[t];
    __syncthreads();

    int tr = t >> 8;                    // 0..1 -> rows tr*4 .. tr*4+3
    int j  = t & 255;
    int js = j & 7;

    float4 uj[8], xj[8];
#pragma unroll
    for (int c = 0; c < 8; ++c) {
        uj[c] = lu4[j * 8 + (c ^ js)];
        xj[c] = lx4[j * 8 + (c ^ js)];
    }

    // uniform (wave-invariant) parameter loads -> scalar regs
    const float4* Wc4 = (const float4*)W_cat;
    float4 wc[8];
#pragma unroll
    for (int c = 0; c < 8; ++c) wc[c] = Wc4[c];
    float f1a[8], f1b[8], fb1[8], f2w[8];
#pragma unroll
    for (int k = 0; k < 8; ++k) {
        f1a[k] = W_f1[k];       // W_f1[0,k]
        f1b[k] = W_f1[8 + k];   // W_f1[1,k]
        fb1[k] = b_f1[k];
        f2w[k] = W_f2[k];
    }
    float bcat = b_cat[0], bf2 = b_f2[0];

    int lane = t & 63;
    int wg   = (t >> 6) & 3;            // wave index within tr-group

#pragma unroll
    for (int r = 0; r < 4; ++r) {
        int il = tr * 4 + r;            // local row 0..7
        int ni = i0 + il;               // row within batch
        int ns = ni & 7;
        float e = 0.f, mp = 0.f;
#pragma unroll
        for (int c = 0; c < 8; ++c) {
            float4 vi = lv4[il * 8 + c];          // broadcast
            float4 xi = lx4[ni * 8 + (c ^ ns)];   // broadcast
            float4 uu = uj[c], xx = xj[c];
            e += fmaxf(uu.x + vi.x, 0.f) * wc[c].x;
            e += fmaxf(uu.y + vi.y, 0.f) * wc[c].y;
            e += fmaxf(uu.z + vi.z, 0.f) * wc[c].z;
            e += fmaxf(uu.w + vi.w, 0.f) * wc[c].w;
            mp += xx.x * xi.x + xx.y * xi.y + xx.z * xi.z + xx.w * xi.w;
        }
        e = fmaxf(e + bcat, 0.f);
        float mlin = (j == ni) ? 0.f : e;
        float s = bf2;
#pragma unroll
        for (int k = 0; k < 8; ++k)
            s += fmaxf(mlin * f1a[k] + mp * f1b[k] + fb1[k], 0.f) * f2w[k];
        float w = 1.f / (1.f + expf(-s));
        float m = w * mlin + (1.f - w) * mp;

        m_out[((size_t)b * NN + ni) * NN + j] = m;

        float sm = m, sq = m * m;
#pragma unroll
        for (int off = 32; off; off >>= 1) {
            sm += __shfl_down(sm, off);
            sq += __shfl_down(sq, off);
        }
        if (lane == 0) { red0[il][wg] = sm; red1[il][wg] = sq; }
    }
    __syncthreads();
    if (t < ROWS) {
        rowsum_out[(size_t)b * NN + i0 + t] = red0[t][0] + red0[t][1] + red0[t][2] + red0[t][3];
        rowsq_out [(size_t)b * NN + i0 + t] = red1[t][0] + red1[t][1] + red1[t][2] + red1[t][3];
    }
}

// ---------------------------------------------------------------------------
// K3: fused stats + finalize. Block = (b, 4 rows), 256 threads.
// Each block redundantly reduces its batch's 256 rowsum/rowsq (2KB, L2-hit)
// to (mu, rstd) via the m2 algebra:
//   sum(m2) = 2*sum(m); sum(m2^2) = sum(m^2) + 3*N*sum_i(rowmean_i^2)
// then out[b,i,j] = (m[b,i,j] + rowmean_i - mu) * rstd.
// ---------------------------------------------------------------------------
__global__ __launch_bounds__(256) void final2_kernel(
    const float* __restrict__ m_in,
    const float* __restrict__ rowsum,
    const float* __restrict__ rowsq,
    float* __restrict__ out)
{
    __shared__ float sred[12];
    __shared__ float stat[2];
    int t  = threadIdx.x;
    int b  = blockIdx.x >> 6;
    int r0 = (blockIdx.x & 63) * 4;

    float rs = rowsum[b * NN + t];
    float rq = rowsq[b * NN + t];
    float rr = rs * (1.f / NN);
    float sM = rs, sQ = rq, sR = rr * rr;
#pragma unroll
    for (int off = 32; off; off >>= 1) {
        sM += __shfl_down(sM, off);
        sQ += __shfl_down(sQ, off);
        sR += __shfl_down(sR, off);
    }
    int wave = t >> 6;
    if ((t & 63) == 0) { sred[wave] = sM; sred[4 + wave] = sQ; sred[8 + wave] = sR; }
    __syncthreads();
    if (t == 0) {
        float sumM  = sred[0] + sred[1] + sred[2] + sred[3];
        float sumQ  = sred[4] + sred[5] + sred[6] + sred[7];
        float sumR2 = sred[8] + sred[9] + sred[10] + sred[11];
        const float inv = 1.f / ((float)NN * (float)NN);
        float mu  = 2.f * sumM * inv;
        float ex2 = (sumQ + 3.f * (float)NN * sumR2) * inv;
        stat[0] = mu;
        stat[1] = rsqrtf(ex2 - mu * mu + 1e-5f);
    }
    __syncthreads();
    float mu = stat[0], rstd = stat[1];
#pragma unroll
    for (int r = 0; r < 4; ++r) {
        int i = r0 + r;
        size_t base = ((size_t)b * NN + i) * NN;
        float ri = rowsum[b * NN + i] * (1.f / NN);
        out[base + t] = (m_in[base + t] + ri - mu) * rstd;
    }
}

extern "C" void kernel_launch(void* const* d_in, const int* in_sizes, int n_in,
                              void* d_out, int out_size, void* d_ws, size_t ws_size,
                              hipStream_t stream)
{
    const float* x     = (const float*)d_in[0];
    const float* W_out = (const float*)d_in[1];
    const float* b_out = (const float*)d_in[2];
    const float* W_cat = (const float*)d_in[3];
    const float* b_cat = (const float*)d_in[4];
    const float* W_f1  = (const float*)d_in[5];
    const float* b_f1  = (const float*)d_in[6];
    const float* W_f2  = (const float*)d_in[7];
    const float* b_f2  = (const float*)d_in[8];

    float* ws     = (float*)d_ws;
    float* u      = ws;                        // BB*NN*DD
    float* v      = u + BB * NN * DD;          // BB*NN*DD
    float* m      = v + BB * NN * DD;          // BB*NN*NN
    float* rowsum = m + (size_t)BB * NN * NN;  // BB*NN
    float* rowsq  = rowsum + BB * NN;          // BB*NN

    precompute_uv<<<BB * NN / 8, 256, 0, stream>>>(x, W_out, b_out, u, v);
    pair2_kernel<<<BB * (NN / ROWS), 512, 0, stream>>>(x, u, v, W_cat, b_cat,
                                                       W_f1, b_f1, W_f2, b_f2,
                                                       m, rowsum, rowsq);
    final2_kernel<<<BB * (NN / 4), 256, 0, stream>>>(m, rowsum, rowsq, (float*)d_out);
}